// Round 2
// baseline (4538.827 us; speedup 1.0000x reference)
//
#include <hip/hip_runtime.h>
#include <hip/hip_bf16.h>

typedef unsigned short u16;
typedef unsigned int u32;

#define N_NODES 100000
#define N_EDGES 600000
#define FIN_D   256
#define HDIM    128
#define NCLS    47
#define NOUT_D  10000

__device__ __forceinline__ float bf2f(u16 u) {
    union { u32 i; float f; } v; v.i = ((u32)u) << 16; return v.f;
}
__device__ __forceinline__ u16 f2bf(float f) {
    __hip_bfloat16 h = __float2bfloat16(f);
    return *reinterpret_cast<u16*>(&h);
}
// dtype-agnostic scalar load: f32 ? fp32 array : bf16 array
__device__ __forceinline__ float loadF(const void* p, size_t i, bool f32) {
    if (f32) return ((const float*)p)[i];
    return bf2f(((const u16*)p)[i]);
}
__device__ __forceinline__ float wave_sum(float v) {
    #pragma unroll
    for (int o = 32; o > 0; o >>= 1) v += __shfl_xor(v, o, 64);
    return v;
}
__device__ __forceinline__ float wave_max(float v) {
    #pragma unroll
    for (int o = 32; o > 0; o >>= 1) v = fmaxf(v, __shfl_xor(v, o, 64));
    return v;
}

// ---------------- dtype detector ---------------------------------------
// bf16 model data never has exponent field >= 200 (|v| >= 2^73); fp32 data
// read as u16 pairs has ~20% such patterns in the low-mantissa halves.
__global__ __launch_bounds__(256) void dtype_detect_kernel(
    const u16* __restrict__ x, int* __restrict__ flag)
{
    __shared__ int cnt;
    if (threadIdx.x == 0) cnt = 0;
    __syncthreads();
    int local = 0;
    for (int i = threadIdx.x; i < 65536; i += 256) {
        u32 e = (x[i] >> 7) & 0xFF;
        if (e >= 200) local++;
    }
    atomicAdd(&cnt, local);
    __syncthreads();
    if (threadIdx.x == 0) *flag = (cnt > 16) ? 1 : 0;
}

// ---------------- LayerNorm + ReLU -> bf16 conv-input copy -------------
__global__ __launch_bounds__(256) void ln_relu_kernel(
    const float* __restrict__ src, const int* __restrict__ map,
    const void* __restrict__ g, const void* __restrict__ b, int goff,
    const int* __restrict__ dt, u16* __restrict__ outHB)
{
    const bool f32 = (*dt != 0);
    int wave = threadIdx.x >> 6;
    int lane = threadIdx.x & 63;
    int row  = blockIdx.x * 4 + wave;
    if (row >= N_NODES) return;
    int srow = map ? map[row] : row;
    const float2* p = (const float2*)(src + (size_t)srow * HDIM);
    float2 v = p[lane];
    float mu = wave_sum(v.x + v.y) * (1.0f / 128.0f);
    float d0 = v.x - mu, d1 = v.y - mu;
    float var = wave_sum(d0 * d0 + d1 * d1) * (1.0f / 128.0f);
    float rs = rsqrtf(var + 1e-5f);
    int f0 = lane * 2;
    float y0 = fmaxf(d0 * rs * loadF(g, goff + f0, f32)     + loadF(b, goff + f0, f32),     0.0f);
    float y1 = fmaxf(d1 * rs * loadF(g, goff + f0 + 1, f32) + loadF(b, goff + f0 + 1, f32), 0.0f);
    u32 pk = (u32)f2bf(y0) | ((u32)f2bf(y1) << 16);
    *((u32*)(outHB + (size_t)row * HDIM + f0)) = pk;
}

// ---------------- Edge softmax accumulation ----------------------------
// ACC layout: [node][feat][2] = {denom += e, num += m*e}. Max-shift skipped
// (softmax is shift-invariant; m in [1e-7, ~8] so exp stays finite in fp32).
__global__ __launch_bounds__(256) void edge_accum_kernel(
    const int* __restrict__ src, const int* __restrict__ dst,
    const u16* __restrict__ HB, float* __restrict__ ACC)
{
    long long gid = (long long)blockIdx.x * 256 + threadIdx.x;
    int e = (int)(gid >> 7);
    int f = (int)(gid & 127);
    if (e >= N_EDGES) return;
    int s = src[e], d = dst[e];
    float m = fmaxf(bf2f(HB[(size_t)s * HDIM + f]), 0.0f) + 1e-7f;
    float p = __expf(m);
    float* base = ACC + (size_t)d * (2 * HDIM) + 2 * f;
    unsafeAtomicAdd(base,     p);
    unsafeAtomicAdd(base + 1, m * p);
}

// ---------------- GEMM: Out[M x 128] = A[M x K] @ B[K x 128] + bias ----
// SRC_MODE 0: A = external x (dtype per flag). 1: A = num/(den+eps)+Hf32.
// 2: A = num/(den+eps)+bf16 HB. Boff/biasoff are ELEMENT offsets into the
// weight arrays (dtype-independent).
template<int SRC_MODE, bool RES, bool WRITE_BF>
__global__ __launch_bounds__(256) void gemm_kernel(
    const void* __restrict__ Araw, const float* __restrict__ ACC,
    const float* __restrict__ Hf32, const u16* __restrict__ Hbf,
    const void* __restrict__ B, int Boff,
    const void* __restrict__ bias, int biasoff,
    const float* __restrict__ Resid, const int* __restrict__ res_map,
    const int* __restrict__ dt,
    float* __restrict__ Out, u16* __restrict__ OutBF,
    int M, int K)
{
    const bool f32 = (*dt != 0);
    __shared__ float Ash[64][64];     // [row][k]
    __shared__ float Bsh[64][128];    // [k][col]
    int tid = threadIdx.x;
    int tr = tid >> 4;
    int tc = tid & 15;
    int m0 = blockIdx.x * 64;

    float acc[4][8];
    #pragma unroll
    for (int r = 0; r < 4; ++r)
        #pragma unroll
        for (int c = 0; c < 8; ++c) acc[r][c] = 0.0f;

    for (int kk = 0; kk < K; kk += 64) {
        #pragma unroll
        for (int i = 0; i < 16; ++i) {
            int lin = i * 256 + tid;
            int row = lin >> 6, kx = lin & 63;
            int grow = m0 + row;
            float v = 0.0f;
            if (grow < M) {
                if (SRC_MODE == 0) {
                    v = loadF(Araw, (size_t)grow * K + kk + kx, f32);
                } else {
                    size_t idx = (size_t)grow * HDIM + kk + kx;
                    float den = ACC[2 * idx], num = ACC[2 * idx + 1];
                    float h = (SRC_MODE == 1) ? Hf32[idx] : bf2f(Hbf[idx]);
                    v = num / (den + 1e-16f) + h;
                }
            }
            Ash[row][kx] = v;
        }
        #pragma unroll
        for (int i = 0; i < 32; ++i) {
            int lin = i * 256 + tid;
            int kr = lin >> 7, col = lin & 127;
            Bsh[kr][col] = loadF(B, (size_t)Boff + (size_t)(kk + kr) * HDIM + col, f32);
        }
        __syncthreads();
        #pragma unroll
        for (int k = 0; k < 64; ++k) {
            float a0 = Ash[tr * 4 + 0][k];
            float a1 = Ash[tr * 4 + 1][k];
            float a2 = Ash[tr * 4 + 2][k];
            float a3 = Ash[tr * 4 + 3][k];
            const float* br = &Bsh[k][tc * 8];
            float4 bv0 = *(const float4*)br;
            float4 bv1 = *(const float4*)(br + 4);
            float bv[8] = {bv0.x, bv0.y, bv0.z, bv0.w, bv1.x, bv1.y, bv1.z, bv1.w};
            #pragma unroll
            for (int c = 0; c < 8; ++c) {
                acc[0][c] = fmaf(a0, bv[c], acc[0][c]);
                acc[1][c] = fmaf(a1, bv[c], acc[1][c]);
                acc[2][c] = fmaf(a2, bv[c], acc[2][c]);
                acc[3][c] = fmaf(a3, bv[c], acc[3][c]);
            }
        }
        __syncthreads();
    }

    #pragma unroll
    for (int r = 0; r < 4; ++r) {
        int row = m0 + tr * 4 + r;
        if (row >= M) continue;
        int col0 = tc * 8;
        size_t rrow = 0;
        if (RES) rrow = (size_t)(res_map ? res_map[row] : row) * HDIM;
        float o[8];
        #pragma unroll
        for (int c = 0; c < 8; ++c) {
            float v = acc[r][c] + loadF(bias, biasoff + col0 + c, f32);
            if (RES) v += Resid[rrow + col0 + c];
            o[c] = v;
        }
        float4* op = (float4*)(Out + (size_t)row * HDIM + col0);
        op[0] = make_float4(o[0], o[1], o[2], o[3]);
        op[1] = make_float4(o[4], o[5], o[6], o[7]);
        if (WRITE_BF) {
            uint4 ob;
            ob.x = (u32)f2bf(o[0]) | ((u32)f2bf(o[1]) << 16);
            ob.y = (u32)f2bf(o[2]) | ((u32)f2bf(o[3]) << 16);
            ob.z = (u32)f2bf(o[4]) | ((u32)f2bf(o[5]) << 16);
            ob.w = (u32)f2bf(o[6]) | ((u32)f2bf(o[7]) << 16);
            *(uint4*)(OutBF + (size_t)row * HDIM + col0) = ob;
        }
    }
}

// ---------------- Final: gather -> LN -> ReLU -> pred -> log_softmax ---
__global__ __launch_bounds__(64) void final_head_kernel(
    const float* __restrict__ Hsrc, const int* __restrict__ map1,
    const int* __restrict__ fmap,
    const void* __restrict__ g, const void* __restrict__ b, int goff,
    const void* __restrict__ pw, const void* __restrict__ pb,
    const int* __restrict__ dt, void* __restrict__ out)
{
    const bool f32 = (*dt != 0);
    __shared__ float sh[HDIM];
    int i = blockIdx.x;
    int lane = threadIdx.x;
    int jj = map1[fmap[i]];
    const float2* p = (const float2*)(Hsrc + (size_t)jj * HDIM);
    float2 v = p[lane];
    float mu = wave_sum(v.x + v.y) * (1.0f / 128.0f);
    float d0 = v.x - mu, d1 = v.y - mu;
    float var = wave_sum(d0 * d0 + d1 * d1) * (1.0f / 128.0f);
    float rs = rsqrtf(var + 1e-5f);
    int f0 = lane * 2;
    sh[f0]     = fmaxf(d0 * rs * loadF(g, goff + f0, f32)     + loadF(b, goff + f0, f32),     0.0f);
    sh[f0 + 1] = fmaxf(d1 * rs * loadF(g, goff + f0 + 1, f32) + loadF(b, goff + f0 + 1, f32), 0.0f);
    __syncthreads();
    float acc = -1e30f;
    if (lane < NCLS) {
        acc = loadF(pb, lane, f32);
        #pragma unroll 4
        for (int k = 0; k < HDIM; ++k)
            acc = fmaf(sh[k], loadF(pw, k * NCLS + lane, f32), acc);
    }
    float mx = wave_max(acc);
    float ex = (lane < NCLS) ? __expf(acc - mx) : 0.0f;
    float sum = wave_sum(ex);
    if (lane < NCLS) {
        float r = acc - mx - logf(sum);
        if (f32) ((float*)out)[(size_t)i * NCLS + lane] = r;
        else     ((u16*)out)[(size_t)i * NCLS + lane] = f2bf(r);
    }
}

extern "C" void kernel_launch(void* const* d_in, const int* in_sizes, int n_in,
                              void* d_out, int out_size, void* d_ws, size_t ws_size,
                              hipStream_t stream) {
    const void* x       = d_in[0];
    const int* src      = (const int*)d_in[1];
    const int* dst      = (const int*)d_in[2];
    const int* node_map = (const int*)d_in[3];
    const int* fmap     = (const int*)d_in[4];
    const void* enc_w   = d_in[5];
    const void* enc_b   = d_in[6];
    const void* gcn_w   = d_in[7];
    const void* gcn_b   = d_in[8];
    const void* ln_g    = d_in[9];
    const void* ln_b    = d_in[10];
    const void* pred_w  = d_in[11];
    const void* pred_b  = d_in[12];

    char* ws = (char*)d_ws;
    const size_t szP = (size_t)N_NODES * HDIM * sizeof(float);   // 51.2 MB
    float* P0  = (float*)ws;            ws += szP;
    float* P1  = (float*)ws;            ws += szP;
    float* ACC = (float*)ws;            ws += 2 * szP;           // {den,num} interleaved
    u16*   HB  = (u16*)ws;              ws += (size_t)N_NODES * HDIM * 2;
    int*   FLAG = (int*)ws;             ws += 256;

    dim3 blk(256);
    int ggrid = (N_NODES + 63) / 64;
    int egrid = (int)(((long long)N_EDGES * HDIM) / 256);   // 300000
    int lgrid = (N_NODES + 3) / 4;

    dtype_detect_kernel<<<1, blk, 0, stream>>>((const u16*)x, FLAG);

    // encoder: P0 = x @ enc_w + enc_b ; HB = bf16(P0)
    gemm_kernel<0, false, true><<<ggrid, blk, 0, stream>>>(
        x, nullptr, nullptr, nullptr, enc_w, 0, enc_b, 0, nullptr, nullptr, FLAG,
        P0, HB, N_NODES, FIN_D);

    // conv0: edges[0], w0/b0, input h0 (P0 fp32 + HB), no residual -> P1
    hipMemsetAsync(ACC, 0, 2 * szP, stream);
    edge_accum_kernel<<<egrid, blk, 0, stream>>>(src, dst, HB, ACC);
    gemm_kernel<1, false, false><<<ggrid, blk, 0, stream>>>(
        nullptr, ACC, P0, nullptr, gcn_w, 0, gcn_b, 0, nullptr, nullptr, FLAG,
        P1, nullptr, N_NODES, HDIM);

    // layer 1: h2 = relu(LN(P1, ln0)); conv on edges[0] w1/b1; +P1 -> P0
    ln_relu_kernel<<<lgrid, blk, 0, stream>>>(P1, nullptr, ln_g, ln_b, 0, FLAG, HB);
    hipMemsetAsync(ACC, 0, 2 * szP, stream);
    edge_accum_kernel<<<egrid, blk, 0, stream>>>(src, dst, HB, ACC);
    gemm_kernel<2, true, false><<<ggrid, blk, 0, stream>>>(
        nullptr, ACC, nullptr, HB, gcn_w, 16384, gcn_b, 128, P1, nullptr, FLAG,
        P0, nullptr, N_NODES, HDIM);

    // layer 2: rows permute via node_map[0]; edges[1] w2/b2; residual via map -> P1
    ln_relu_kernel<<<lgrid, blk, 0, stream>>>(P0, node_map, ln_g, ln_b, 128, FLAG, HB);
    hipMemsetAsync(ACC, 0, 2 * szP, stream);
    edge_accum_kernel<<<egrid, blk, 0, stream>>>(src + N_EDGES, dst + N_EDGES, HB, ACC);
    gemm_kernel<2, true, false><<<ggrid, blk, 0, stream>>>(
        nullptr, ACC, nullptr, HB, gcn_w, 32768, gcn_b, 256, P0, node_map, FLAG,
        P1, nullptr, N_NODES, HDIM);

    // final head: rows P1[node_map[1][final_map[i]]] -> LN(ln2) -> pred -> log_softmax
    final_head_kernel<<<NOUT_D, dim3(64), 0, stream>>>(
        P1, node_map + N_NODES, fmap, ln_g, ln_b, 256, pred_w, pred_b, FLAG,
        (void*)d_out);
}

// Round 3
// 1907.834 us; speedup vs baseline: 2.3790x; 2.3790x over previous
//
#include <hip/hip_runtime.h>
#include <hip/hip_bf16.h>

typedef unsigned short u16;
typedef unsigned int u32;

#define N_NODES 100000
#define N_EDGES 600000
#define FIN_D   256
#define HDIM    128
#define NCLS    47
#define NOUT_D  10000
#define NCHUNK  196          // ceil(N_NODES/512)

__device__ __forceinline__ float bf2f(u16 u) {
    union { u32 i; float f; } v; v.i = ((u32)u) << 16; return v.f;
}
__device__ __forceinline__ u16 f2bf(float f) {
    __hip_bfloat16 h = __float2bfloat16(f);
    return *reinterpret_cast<u16*>(&h);
}
__device__ __forceinline__ float loadF(const void* p, size_t i, bool f32) {
    if (f32) return ((const float*)p)[i];
    return bf2f(((const u16*)p)[i]);
}
__device__ __forceinline__ float wave_sum(float v) {
    #pragma unroll
    for (int o = 32; o > 0; o >>= 1) v += __shfl_xor(v, o, 64);
    return v;
}
__device__ __forceinline__ float wave_max(float v) {
    #pragma unroll
    for (int o = 32; o > 0; o >>= 1) v = fmaxf(v, __shfl_xor(v, o, 64));
    return v;
}
__device__ __forceinline__ int wave_sum_i(int v) {
    #pragma unroll
    for (int o = 32; o > 0; o >>= 1) v += __shfl_xor(v, o, 64);
    return v;
}
// exclusive scan over a 256-thread block; wsum = shared int[4]
__device__ __forceinline__ int block_excl_scan_256(int v, int* wsum) {
    int lane = threadIdx.x & 63, wv = threadIdx.x >> 6;
    int inc = v;
    #pragma unroll
    for (int off = 1; off < 64; off <<= 1) {
        int u = __shfl_up(inc, off, 64);
        if (lane >= off) inc += u;
    }
    if (lane == 63) wsum[wv] = inc;
    __syncthreads();
    if (threadIdx.x == 0) {
        int a = 0;
        #pragma unroll
        for (int w = 0; w < 4; ++w) { int t = wsum[w]; wsum[w] = a; a += t; }
    }
    __syncthreads();
    return inc - v + wsum[wv];
}

// ---------------- dtype detector ---------------------------------------
__global__ __launch_bounds__(256) void dtype_detect_kernel(
    const u16* __restrict__ x, int* __restrict__ flag)
{
    __shared__ int cnt;
    if (threadIdx.x == 0) cnt = 0;
    __syncthreads();
    int local = 0;
    for (int i = threadIdx.x; i < 65536; i += 256) {
        u32 e = (x[i] >> 7) & 0xFF;
        if (e >= 200) local++;
    }
    atomicAdd(&cnt, local);
    __syncthreads();
    if (threadIdx.x == 0) *flag = (cnt > 16) ? 1 : 0;
}

// ---------------- CSR build --------------------------------------------
__global__ __launch_bounds__(256) void hist_kernel(
    const int* __restrict__ dst, int* __restrict__ deg)
{
    int e = blockIdx.x * 256 + threadIdx.x;
    if (e < N_EDGES) atomicAdd(&deg[dst[e]], 1);
}

__global__ __launch_bounds__(256) void chunk_sum_kernel(
    const int* __restrict__ deg, int* __restrict__ chunk_sum)
{
    __shared__ int ws[4];
    int i0 = blockIdx.x * 512 + threadIdx.x;
    int v = 0;
    if (i0 < N_NODES) v += deg[i0];
    if (i0 + 256 < N_NODES) v += deg[i0 + 256];
    v = wave_sum_i(v);
    int lane = threadIdx.x & 63, wv = threadIdx.x >> 6;
    if (lane == 0) ws[wv] = v;
    __syncthreads();
    if (threadIdx.x == 0)
        chunk_sum[blockIdx.x] = ws[0] + ws[1] + ws[2] + ws[3];
}

__global__ __launch_bounds__(256) void chunk_off_kernel(
    const int* __restrict__ chunk_sum, int* __restrict__ chunk_off)
{
    __shared__ int wsum[4];
    int t = threadIdx.x;
    int v = (t < NCHUNK) ? chunk_sum[t] : 0;
    int excl = block_excl_scan_256(v, wsum);
    if (t < NCHUNK) chunk_off[t] = excl;
}

__global__ __launch_bounds__(256) void scan_write_kernel(
    const int* __restrict__ deg, const int* __restrict__ chunk_off,
    int* __restrict__ row_ptr, int* __restrict__ cursor)
{
    __shared__ int wsum[4];
    int b = blockIdx.x, t = threadIdx.x;
    int i0 = b * 512 + 2 * t;
    int d0 = (i0 < N_NODES) ? deg[i0] : 0;
    int d1 = (i0 + 1 < N_NODES) ? deg[i0 + 1] : 0;
    int excl = block_excl_scan_256(d0 + d1, wsum);
    int base = chunk_off[b] + excl;
    if (i0 < N_NODES)     { row_ptr[i0] = base;          cursor[i0] = base; }
    if (i0 + 1 < N_NODES) { row_ptr[i0 + 1] = base + d0; cursor[i0 + 1] = base + d0; }
    if (b == 0 && t == 0) row_ptr[N_NODES] = N_EDGES;
}

__global__ __launch_bounds__(256) void scatter_kernel(
    const int* __restrict__ src, const int* __restrict__ dst,
    int* __restrict__ cursor, int* __restrict__ eidx)
{
    int e = blockIdx.x * 256 + threadIdx.x;
    if (e >= N_EDGES) return;
    int d = dst[e];
    int pos = atomicAdd(&cursor[d], 1);
    eidx[pos] = src[e];
}

// ---------------- Softmax aggregation, CSR gather (no float atomics) ---
// Wave per dst node; lane handles 2 features. agg = (Σ m·e)/(Σ e + 1e-16),
// m = relu(h_src)+1e-7, max-shift skipped (shift-invariant, m bounded).
__global__ __launch_bounds__(256) void agg_kernel(
    const int* __restrict__ row_ptr, const int* __restrict__ eidx,
    const u16* __restrict__ HB, float* __restrict__ AGG)
{
    int wave = threadIdx.x >> 6;
    int lane = threadIdx.x & 63;
    int n = blockIdx.x * 4 + wave;
    if (n >= N_NODES) return;
    int beg = row_ptr[n], end = row_ptr[n + 1];
    const u32* HB32 = (const u32*)HB;
    float den0 = 0.f, den1 = 0.f, num0 = 0.f, num1 = 0.f;
    for (int j = beg; j < end; ++j) {
        int s = eidx[j];
        u32 h = HB32[(size_t)s * 64 + lane];
        float m0 = fmaxf(bf2f((u16)(h & 0xffff)), 0.f) + 1e-7f;
        float m1 = fmaxf(bf2f((u16)(h >> 16)),    0.f) + 1e-7f;
        float e0 = __expf(m0), e1 = __expf(m1);
        den0 += e0; num0 += m0 * e0;
        den1 += e1; num1 += m1 * e1;
    }
    float2 o;
    o.x = num0 / (den0 + 1e-16f);
    o.y = num1 / (den1 + 1e-16f);
    ((float2*)(AGG + (size_t)n * HDIM))[lane] = o;
}

// ---------------- LayerNorm + ReLU -> bf16 conv-input copy -------------
__global__ __launch_bounds__(256) void ln_relu_kernel(
    const float* __restrict__ src, const int* __restrict__ map,
    const void* __restrict__ g, const void* __restrict__ b, int goff,
    const int* __restrict__ dt, u16* __restrict__ outHB)
{
    const bool f32 = (*dt != 0);
    int wave = threadIdx.x >> 6;
    int lane = threadIdx.x & 63;
    int row  = blockIdx.x * 4 + wave;
    if (row >= N_NODES) return;
    int srow = map ? map[row] : row;
    const float2* p = (const float2*)(src + (size_t)srow * HDIM);
    float2 v = p[lane];
    float mu = wave_sum(v.x + v.y) * (1.0f / 128.0f);
    float d0 = v.x - mu, d1 = v.y - mu;
    float var = wave_sum(d0 * d0 + d1 * d1) * (1.0f / 128.0f);
    float rs = rsqrtf(var + 1e-5f);
    int f0 = lane * 2;
    float y0 = fmaxf(d0 * rs * loadF(g, goff + f0, f32)     + loadF(b, goff + f0, f32),     0.0f);
    float y1 = fmaxf(d1 * rs * loadF(g, goff + f0 + 1, f32) + loadF(b, goff + f0 + 1, f32), 0.0f);
    u32 pk = (u32)f2bf(y0) | ((u32)f2bf(y1) << 16);
    *((u32*)(outHB + (size_t)row * HDIM + f0)) = pk;
}

// ---------------- GEMM: Out[M x 128] = A[M x K] @ B[K x 128] + bias ----
// SRC_MODE 0: A = external x (dtype per flag). 1: A = AGG + Hf32 (conv0).
// 2: A = AGG + bf16 HB (layers 1,2). Boff/biasoff: ELEMENT offsets.
template<int SRC_MODE, bool RES, bool WRITE_BF>
__global__ __launch_bounds__(256) void gemm_kernel(
    const void* __restrict__ Araw, const float* __restrict__ AGG,
    const float* __restrict__ Hf32, const u16* __restrict__ Hbf,
    const void* __restrict__ B, int Boff,
    const void* __restrict__ bias, int biasoff,
    const float* __restrict__ Resid, const int* __restrict__ res_map,
    const int* __restrict__ dt,
    float* __restrict__ Out, u16* __restrict__ OutBF,
    int M, int K)
{
    const bool f32 = (*dt != 0);
    __shared__ float Ash[64][64];
    __shared__ float Bsh[64][128];
    int tid = threadIdx.x;
    int tr = tid >> 4;
    int tc = tid & 15;
    int m0 = blockIdx.x * 64;

    float acc[4][8];
    #pragma unroll
    for (int r = 0; r < 4; ++r)
        #pragma unroll
        for (int c = 0; c < 8; ++c) acc[r][c] = 0.0f;

    for (int kk = 0; kk < K; kk += 64) {
        #pragma unroll
        for (int i = 0; i < 16; ++i) {
            int lin = i * 256 + tid;
            int row = lin >> 6, kx = lin & 63;
            int grow = m0 + row;
            float v = 0.0f;
            if (grow < M) {
                if (SRC_MODE == 0) {
                    v = loadF(Araw, (size_t)grow * K + kk + kx, f32);
                } else {
                    size_t idx = (size_t)grow * HDIM + kk + kx;
                    float h = (SRC_MODE == 1) ? Hf32[idx] : bf2f(Hbf[idx]);
                    v = AGG[idx] + h;
                }
            }
            Ash[row][kx] = v;
        }
        #pragma unroll
        for (int i = 0; i < 32; ++i) {
            int lin = i * 256 + tid;
            int kr = lin >> 7, col = lin & 127;
            Bsh[kr][col] = loadF(B, (size_t)Boff + (size_t)(kk + kr) * HDIM + col, f32);
        }
        __syncthreads();
        #pragma unroll
        for (int k = 0; k < 64; ++k) {
            float a0 = Ash[tr * 4 + 0][k];
            float a1 = Ash[tr * 4 + 1][k];
            float a2 = Ash[tr * 4 + 2][k];
            float a3 = Ash[tr * 4 + 3][k];
            const float* br = &Bsh[k][tc * 8];
            float4 bv0 = *(const float4*)br;
            float4 bv1 = *(const float4*)(br + 4);
            float bv[8] = {bv0.x, bv0.y, bv0.z, bv0.w, bv1.x, bv1.y, bv1.z, bv1.w};
            #pragma unroll
            for (int c = 0; c < 8; ++c) {
                acc[0][c] = fmaf(a0, bv[c], acc[0][c]);
                acc[1][c] = fmaf(a1, bv[c], acc[1][c]);
                acc[2][c] = fmaf(a2, bv[c], acc[2][c]);
                acc[3][c] = fmaf(a3, bv[c], acc[3][c]);
            }
        }
        __syncthreads();
    }

    #pragma unroll
    for (int r = 0; r < 4; ++r) {
        int row = m0 + tr * 4 + r;
        if (row >= M) continue;
        int col0 = tc * 8;
        size_t rrow = 0;
        if (RES) rrow = (size_t)(res_map ? res_map[row] : row) * HDIM;
        float o[8];
        #pragma unroll
        for (int c = 0; c < 8; ++c) {
            float v = acc[r][c] + loadF(bias, biasoff + col0 + c, f32);
            if (RES) v += Resid[rrow + col0 + c];
            o[c] = v;
        }
        float4* op = (float4*)(Out + (size_t)row * HDIM + col0);
        op[0] = make_float4(o[0], o[1], o[2], o[3]);
        op[1] = make_float4(o[4], o[5], o[6], o[7]);
        if (WRITE_BF) {
            uint4 ob;
            ob.x = (u32)f2bf(o[0]) | ((u32)f2bf(o[1]) << 16);
            ob.y = (u32)f2bf(o[2]) | ((u32)f2bf(o[3]) << 16);
            ob.z = (u32)f2bf(o[4]) | ((u32)f2bf(o[5]) << 16);
            ob.w = (u32)f2bf(o[6]) | ((u32)f2bf(o[7]) << 16);
            *(uint4*)(OutBF + (size_t)row * HDIM + col0) = ob;
        }
    }
}

// ---------------- Final: gather -> LN -> ReLU -> pred -> log_softmax ---
__global__ __launch_bounds__(64) void final_head_kernel(
    const float* __restrict__ Hsrc, const int* __restrict__ map1,
    const int* __restrict__ fmap,
    const void* __restrict__ g, const void* __restrict__ b, int goff,
    const void* __restrict__ pw, const void* __restrict__ pb,
    const int* __restrict__ dt, void* __restrict__ out)
{
    const bool f32 = (*dt != 0);
    __shared__ float sh[HDIM];
    int i = blockIdx.x;
    int lane = threadIdx.x;
    int jj = map1[fmap[i]];
    const float2* p = (const float2*)(Hsrc + (size_t)jj * HDIM);
    float2 v = p[lane];
    float mu = wave_sum(v.x + v.y) * (1.0f / 128.0f);
    float d0 = v.x - mu, d1 = v.y - mu;
    float var = wave_sum(d0 * d0 + d1 * d1) * (1.0f / 128.0f);
    float rs = rsqrtf(var + 1e-5f);
    int f0 = lane * 2;
    sh[f0]     = fmaxf(d0 * rs * loadF(g, goff + f0, f32)     + loadF(b, goff + f0, f32),     0.0f);
    sh[f0 + 1] = fmaxf(d1 * rs * loadF(g, goff + f0 + 1, f32) + loadF(b, goff + f0 + 1, f32), 0.0f);
    __syncthreads();
    float acc = -1e30f;
    if (lane < NCLS) {
        acc = loadF(pb, lane, f32);
        #pragma unroll 4
        for (int k = 0; k < HDIM; ++k)
            acc = fmaf(sh[k], loadF(pw, k * NCLS + lane, f32), acc);
    }
    float mx = wave_max(acc);
    float ex = (lane < NCLS) ? __expf(acc - mx) : 0.0f;
    float sum = wave_sum(ex);
    if (lane < NCLS) {
        float r = acc - mx - logf(sum);
        if (f32) ((float*)out)[(size_t)i * NCLS + lane] = r;
        else     ((u16*)out)[(size_t)i * NCLS + lane] = f2bf(r);
    }
}

extern "C" void kernel_launch(void* const* d_in, const int* in_sizes, int n_in,
                              void* d_out, int out_size, void* d_ws, size_t ws_size,
                              hipStream_t stream) {
    const void* x       = d_in[0];
    const int* src      = (const int*)d_in[1];
    const int* dst      = (const int*)d_in[2];
    const int* node_map = (const int*)d_in[3];
    const int* fmap     = (const int*)d_in[4];
    const void* enc_w   = d_in[5];
    const void* enc_b   = d_in[6];
    const void* gcn_w   = d_in[7];
    const void* gcn_b   = d_in[8];
    const void* ln_g    = d_in[9];
    const void* ln_b    = d_in[10];
    const void* pred_w  = d_in[11];
    const void* pred_b  = d_in[12];

    char* ws = (char*)d_ws;
    const size_t szP = (size_t)N_NODES * HDIM * sizeof(float);   // 51.2 MB
    float* P0  = (float*)ws;  ws += szP;
    float* P1  = (float*)ws;  ws += szP;
    float* AGG = (float*)ws;  ws += szP;
    u16*   HB  = (u16*)ws;    ws += (size_t)N_NODES * HDIM * 2;  // 25.6 MB
    int*   FLAG = (int*)ws;   ws += 1024;
    // CSR buffers (per edge list)
    const size_t szI = ((size_t)(N_NODES + 2) * 4 + 1023) & ~1023ull;
    int* deg0  = (int*)ws;  ws += szI;
    int* rp0   = (int*)ws;  ws += szI;
    int* cur0  = (int*)ws;  ws += szI;
    int* ei0   = (int*)ws;  ws += (size_t)N_EDGES * 4;
    int* deg1  = (int*)ws;  ws += szI;
    int* rp1   = (int*)ws;  ws += szI;
    int* cur1  = (int*)ws;  ws += szI;
    int* ei1   = (int*)ws;  ws += (size_t)N_EDGES * 4;
    int* csum  = (int*)ws;  ws += 1024;
    int* coff  = (int*)ws;  ws += 1024;

    dim3 blk(256);
    const int ggrid = (N_NODES + 63) / 64;
    const int egrid = (N_EDGES + 255) / 256;
    const int lgrid = (N_NODES + 3) / 4;

    dtype_detect_kernel<<<1, blk, 0, stream>>>((const u16*)x, FLAG);

    // ---- CSR for edge list 0 (used by layers 0 and 1) ----
    hipMemsetAsync(deg0, 0, szI, stream);
    hist_kernel<<<egrid, blk, 0, stream>>>(dst, deg0);
    chunk_sum_kernel<<<NCHUNK, blk, 0, stream>>>(deg0, csum);
    chunk_off_kernel<<<1, blk, 0, stream>>>(csum, coff);
    scan_write_kernel<<<NCHUNK, blk, 0, stream>>>(deg0, coff, rp0, cur0);
    scatter_kernel<<<egrid, blk, 0, stream>>>(src, dst, cur0, ei0);
    // ---- CSR for edge list 1 (layer 2) ----
    hipMemsetAsync(deg1, 0, szI, stream);
    hist_kernel<<<egrid, blk, 0, stream>>>(dst + N_EDGES, deg1);
    chunk_sum_kernel<<<NCHUNK, blk, 0, stream>>>(deg1, csum);
    chunk_off_kernel<<<1, blk, 0, stream>>>(csum, coff);
    scan_write_kernel<<<NCHUNK, blk, 0, stream>>>(deg1, coff, rp1, cur1);
    scatter_kernel<<<egrid, blk, 0, stream>>>(src + N_EDGES, dst + N_EDGES, cur1, ei1);

    // encoder: P0 = x @ enc_w + enc_b ; HB = bf16(P0)
    gemm_kernel<0, false, true><<<ggrid, blk, 0, stream>>>(
        x, nullptr, nullptr, nullptr, enc_w, 0, enc_b, 0, nullptr, nullptr, FLAG,
        P0, HB, N_NODES, FIN_D);

    // conv0: AGG from CSR0 over HB; P1 = (AGG + P0) @ w0 + b0
    agg_kernel<<<lgrid, blk, 0, stream>>>(rp0, ei0, HB, AGG);
    gemm_kernel<1, false, false><<<ggrid, blk, 0, stream>>>(
        nullptr, AGG, P0, nullptr, gcn_w, 0, gcn_b, 0, nullptr, nullptr, FLAG,
        P1, nullptr, N_NODES, HDIM);

    // layer 1: HB = relu(LN(P1, ln0)); AGG from CSR0; P0 = (AGG+HB)@w1+b1 + P1
    ln_relu_kernel<<<lgrid, blk, 0, stream>>>(P1, nullptr, ln_g, ln_b, 0, FLAG, HB);
    agg_kernel<<<lgrid, blk, 0, stream>>>(rp0, ei0, HB, AGG);
    gemm_kernel<2, true, false><<<ggrid, blk, 0, stream>>>(
        nullptr, AGG, nullptr, HB, gcn_w, 16384, gcn_b, 128, P1, nullptr, FLAG,
        P0, nullptr, N_NODES, HDIM);

    // layer 2: rows via node_map[0]; CSR1; P1 = (AGG+HB)@w2+b2 + P0[map]
    ln_relu_kernel<<<lgrid, blk, 0, stream>>>(P0, node_map, ln_g, ln_b, 128, FLAG, HB);
    agg_kernel<<<lgrid, blk, 0, stream>>>(rp1, ei1, HB, AGG);
    gemm_kernel<2, true, false><<<ggrid, blk, 0, stream>>>(
        nullptr, AGG, nullptr, HB, gcn_w, 32768, gcn_b, 256, P0, node_map, FLAG,
        P1, nullptr, N_NODES, HDIM);

    // final head: P1[node_map[1][final_map[i]]] -> LN(ln2) -> pred -> log_softmax
    final_head_kernel<<<NOUT_D, dim3(64), 0, stream>>>(
        P1, node_map + N_NODES, fmap, ln_g, ln_b, 256, pred_w, pred_b, FLAG,
        (void*)d_out);
}

// Round 4
// 882.235 us; speedup vs baseline: 5.1447x; 2.1625x over previous
//
#include <hip/hip_runtime.h>
#include <hip/hip_bf16.h>

typedef unsigned short u16;
typedef unsigned int u32;

#define N_NODES 100000
#define N_EDGES 600000
#define FIN_D   256
#define HDIM    128
#define NCLS    47
#define NOUT_D  10000
#define NCHUNK  196          // ceil(N_NODES/512)

typedef short bf16x8 __attribute__((ext_vector_type(8)));
typedef float f32x4  __attribute__((ext_vector_type(4)));

__device__ __forceinline__ float bf2f(u16 u) {
    union { u32 i; float f; } v; v.i = ((u32)u) << 16; return v.f;
}
__device__ __forceinline__ u16 f2bf(float f) {
    __hip_bfloat16 h = __float2bfloat16(f);
    return *reinterpret_cast<u16*>(&h);
}
__device__ __forceinline__ float loadF(const void* p, size_t i, bool f32) {
    if (f32) return ((const float*)p)[i];
    return bf2f(((const u16*)p)[i]);
}
__device__ __forceinline__ float wave_sum(float v) {
    #pragma unroll
    for (int o = 32; o > 0; o >>= 1) v += __shfl_xor(v, o, 64);
    return v;
}
__device__ __forceinline__ float wave_max(float v) {
    #pragma unroll
    for (int o = 32; o > 0; o >>= 1) v = fmaxf(v, __shfl_xor(v, o, 64));
    return v;
}
__device__ __forceinline__ int wave_sum_i(int v) {
    #pragma unroll
    for (int o = 32; o > 0; o >>= 1) v += __shfl_xor(v, o, 64);
    return v;
}
__device__ __forceinline__ int block_excl_scan_256(int v, int* wsum) {
    int lane = threadIdx.x & 63, wv = threadIdx.x >> 6;
    int inc = v;
    #pragma unroll
    for (int off = 1; off < 64; off <<= 1) {
        int u = __shfl_up(inc, off, 64);
        if (lane >= off) inc += u;
    }
    if (lane == 63) wsum[wv] = inc;
    __syncthreads();
    if (threadIdx.x == 0) {
        int a = 0;
        #pragma unroll
        for (int w = 0; w < 4; ++w) { int t = wsum[w]; wsum[w] = a; a += t; }
    }
    __syncthreads();
    return inc - v + wsum[wv];
}

// ---------------- dtype detector ---------------------------------------
__global__ __launch_bounds__(256) void dtype_detect_kernel(
    const u16* __restrict__ x, int* __restrict__ flag)
{
    __shared__ int cnt;
    if (threadIdx.x == 0) cnt = 0;
    __syncthreads();
    int local = 0;
    for (int i = threadIdx.x; i < 65536; i += 256) {
        u32 e = (x[i] >> 7) & 0xFF;
        if (e >= 200) local++;
    }
    atomicAdd(&cnt, local);
    __syncthreads();
    if (threadIdx.x == 0) *flag = (cnt > 16) ? 1 : 0;
}

// ---------------- CSR build --------------------------------------------
__global__ __launch_bounds__(256) void hist_kernel(
    const int* __restrict__ dst, int* __restrict__ deg)
{
    int e = blockIdx.x * 256 + threadIdx.x;
    if (e < N_EDGES) atomicAdd(&deg[dst[e]], 1);
}

__global__ __launch_bounds__(256) void chunk_sum_kernel(
    const int* __restrict__ deg, int* __restrict__ chunk_sum)
{
    __shared__ int ws[4];
    int i0 = blockIdx.x * 512 + threadIdx.x;
    int v = 0;
    if (i0 < N_NODES) v += deg[i0];
    if (i0 + 256 < N_NODES) v += deg[i0 + 256];
    v = wave_sum_i(v);
    int lane = threadIdx.x & 63, wv = threadIdx.x >> 6;
    if (lane == 0) ws[wv] = v;
    __syncthreads();
    if (threadIdx.x == 0)
        chunk_sum[blockIdx.x] = ws[0] + ws[1] + ws[2] + ws[3];
}

__global__ __launch_bounds__(256) void chunk_off_kernel(
    const int* __restrict__ chunk_sum, int* __restrict__ chunk_off)
{
    __shared__ int wsum[4];
    int t = threadIdx.x;
    int v = (t < NCHUNK) ? chunk_sum[t] : 0;
    int excl = block_excl_scan_256(v, wsum);
    if (t < NCHUNK) chunk_off[t] = excl;
}

__global__ __launch_bounds__(256) void scan_write_kernel(
    const int* __restrict__ deg, const int* __restrict__ chunk_off,
    int* __restrict__ row_ptr, int* __restrict__ cursor)
{
    __shared__ int wsum[4];
    int b = blockIdx.x, t = threadIdx.x;
    int i0 = b * 512 + 2 * t;
    int d0 = (i0 < N_NODES) ? deg[i0] : 0;
    int d1 = (i0 + 1 < N_NODES) ? deg[i0 + 1] : 0;
    int excl = block_excl_scan_256(d0 + d1, wsum);
    int base = chunk_off[b] + excl;
    if (i0 < N_NODES)     { row_ptr[i0] = base;          cursor[i0] = base; }
    if (i0 + 1 < N_NODES) { row_ptr[i0 + 1] = base + d0; cursor[i0 + 1] = base + d0; }
    if (b == 0 && t == 0) row_ptr[N_NODES] = N_EDGES;
}

__global__ __launch_bounds__(256) void scatter_kernel(
    const int* __restrict__ src, const int* __restrict__ dst,
    int* __restrict__ cursor, int* __restrict__ eidx)
{
    int e = blockIdx.x * 256 + threadIdx.x;
    if (e >= N_EDGES) return;
    int d = dst[e];
    int pos = atomicAdd(&cursor[d], 1);
    eidx[pos] = src[e];
}

// ---------------- Softmax aggregation, CSR gather ----------------------
__global__ __launch_bounds__(256) void agg_kernel(
    const int* __restrict__ row_ptr, const int* __restrict__ eidx,
    const u16* __restrict__ HB, float* __restrict__ AGG)
{
    int wave = threadIdx.x >> 6;
    int lane = threadIdx.x & 63;
    int n = blockIdx.x * 4 + wave;
    if (n >= N_NODES) return;
    int beg = row_ptr[n], end = row_ptr[n + 1];
    const u32* HB32 = (const u32*)HB;
    float den0 = 0.f, den1 = 0.f, num0 = 0.f, num1 = 0.f;
    for (int j = beg; j < end; ++j) {
        int s = eidx[j];
        u32 h = HB32[(size_t)s * 64 + lane];
        float m0 = fmaxf(bf2f((u16)(h & 0xffff)), 0.f) + 1e-7f;
        float m1 = fmaxf(bf2f((u16)(h >> 16)),    0.f) + 1e-7f;
        float e0 = __expf(m0), e1 = __expf(m1);
        den0 += e0; num0 += m0 * e0;
        den1 += e1; num1 += m1 * e1;
    }
    float2 o;
    o.x = num0 / (den0 + 1e-16f);
    o.y = num1 / (den1 + 1e-16f);
    ((float2*)(AGG + (size_t)n * HDIM))[lane] = o;
}

// ---------------- LayerNorm + ReLU -> bf16 conv-input copy -------------
__global__ __launch_bounds__(256) void ln_relu_kernel(
    const float* __restrict__ src, const int* __restrict__ map,
    const void* __restrict__ g, const void* __restrict__ b, int goff,
    const int* __restrict__ dt, u16* __restrict__ outHB)
{
    const bool f32 = (*dt != 0);
    int wave = threadIdx.x >> 6;
    int lane = threadIdx.x & 63;
    int row  = blockIdx.x * 4 + wave;
    if (row >= N_NODES) return;
    int srow = map ? map[row] : row;
    const float2* p = (const float2*)(src + (size_t)srow * HDIM);
    float2 v = p[lane];
    float mu = wave_sum(v.x + v.y) * (1.0f / 128.0f);
    float d0 = v.x - mu, d1 = v.y - mu;
    float var = wave_sum(d0 * d0 + d1 * d1) * (1.0f / 128.0f);
    float rs = rsqrtf(var + 1e-5f);
    int f0 = lane * 2;
    float y0 = fmaxf(d0 * rs * loadF(g, goff + f0, f32)     + loadF(b, goff + f0, f32),     0.0f);
    float y1 = fmaxf(d1 * rs * loadF(g, goff + f0 + 1, f32) + loadF(b, goff + f0 + 1, f32), 0.0f);
    u32 pk = (u32)f2bf(y0) | ((u32)f2bf(y1) << 16);
    *((u32*)(outHB + (size_t)row * HDIM + f0)) = pk;
}

// ---------------- Weight pre-pack into MFMA B-fragment order -----------
// Packed element o = ((kidx*8 + ct)*64 + lane)*8 + j  maps to
// B[k = kidx*32 + (lane>>4)*8 + j][n = ct*16 + (lane&15)].
// Layout: enc (K=256) at [0, 32768); gcn layer l (K=128) at 32768+l*16384.
__global__ __launch_bounds__(256) void pack_b_kernel(
    const void* __restrict__ enc_w, const void* __restrict__ gcn_w,
    const int* __restrict__ dt, u16* __restrict__ Bp)
{
    const bool f32 = (*dt != 0);
    int o = blockIdx.x * 256 + threadIdx.x;
    if (o >= 32768 + 3 * 16384) return;
    const void* srcp; size_t soff; int m;
    if (o < 32768) { srcp = enc_w; soff = 0; m = o; }
    else {
        int l = (o - 32768) >> 14;
        srcp = gcn_w; soff = (size_t)l * 16384; m = (o - 32768) & 16383;
    }
    int j    = m & 7;
    int lane = (m >> 3) & 63;
    int ct   = (m >> 9) & 7;
    int kidx = m >> 12;
    int k = kidx * 32 + (lane >> 4) * 8 + j;
    int n = ct * 16 + (lane & 15);
    Bp[o] = f2bf(loadF(srcp, soff + (size_t)k * HDIM + n, f32));
}

// ---------------- MFMA GEMM: Out[M x 128] = A[M x K] @ B + bias --------
// SRC_MODE 0: A = external x (dtype per flag). 1: A = AGG + Hf32.
// 2: A = AGG + bf16 HB. B from pre-packed Bp (element offset Bpbase).
// 128-row tile/block, 4 waves, each wave: 32 rows x 128 cols.
template<int SRC_MODE, bool RES, bool WRITE_BF>
__global__ __launch_bounds__(256) void gemm_kernel(
    const void* __restrict__ Araw, const float* __restrict__ AGG,
    const float* __restrict__ Hf32, const u16* __restrict__ Hbf,
    const u16* __restrict__ Bp, int Bpbase,
    const void* __restrict__ bias, int biasoff,
    const float* __restrict__ Resid, const int* __restrict__ res_map,
    const int* __restrict__ dt,
    float* __restrict__ Out, u16* __restrict__ OutBF,
    int M, int K)
{
    const bool f32 = (*dt != 0);
    __shared__ u16 Ash[128][72];          // bf16 A tile, +8 pad (16B-aligned rows)
    const int tid  = threadIdx.x;
    const int w    = tid >> 6;
    const int lane = tid & 63;
    const int quad = lane >> 4;
    const int cl   = lane & 15;
    const int m0   = blockIdx.x * 128;

    f32x4 acc[2][8];
    #pragma unroll
    for (int rt = 0; rt < 2; ++rt)
        #pragma unroll
        for (int ct = 0; ct < 8; ++ct) acc[rt][ct] = (f32x4){0.f, 0.f, 0.f, 0.f};

    for (int kk = 0; kk < K; kk += 64) {
        // ---- stage A tile (128 x 64) as bf16 ----
        #pragma unroll
        for (int i = 0; i < 8; ++i) {
            int lin = i * 256 + tid;
            int row = lin >> 4;
            int kq  = (lin & 15) * 4;
            int grow = m0 + row;
            uint2 pk = make_uint2(0u, 0u);
            if (grow < M) {
                if (SRC_MODE == 0) {
                    if (!f32) {
                        pk = *(const uint2*)((const u16*)Araw + (size_t)grow * K + kk + kq);
                    } else {
                        float4 v = *(const float4*)((const float*)Araw + (size_t)grow * K + kk + kq);
                        pk.x = (u32)f2bf(v.x) | ((u32)f2bf(v.y) << 16);
                        pk.y = (u32)f2bf(v.z) | ((u32)f2bf(v.w) << 16);
                    }
                } else {
                    size_t idx = (size_t)grow * HDIM + kk + kq;
                    float4 a = *(const float4*)(AGG + idx);
                    float h0, h1, h2, h3;
                    if (SRC_MODE == 1) {
                        float4 h = *(const float4*)(Hf32 + idx);
                        h0 = h.x; h1 = h.y; h2 = h.z; h3 = h.w;
                    } else {
                        uint2 hb = *(const uint2*)(Hbf + idx);
                        h0 = bf2f((u16)(hb.x & 0xffff)); h1 = bf2f((u16)(hb.x >> 16));
                        h2 = bf2f((u16)(hb.y & 0xffff)); h3 = bf2f((u16)(hb.y >> 16));
                    }
                    pk.x = (u32)f2bf(a.x + h0) | ((u32)f2bf(a.y + h1) << 16);
                    pk.y = (u32)f2bf(a.z + h2) | ((u32)f2bf(a.w + h3) << 16);
                }
            }
            *(uint2*)&Ash[row][kq] = pk;
        }
        __syncthreads();

        // ---- MFMA over this K-slab (two K=32 steps) ----
        #pragma unroll
        for (int ks = 0; ks < 2; ++ks) {
            bf16x8 a0 = *(const bf16x8*)&Ash[w * 32 +  0 + cl][ks * 32 + quad * 8];
            bf16x8 a1 = *(const bf16x8*)&Ash[w * 32 + 16 + cl][ks * 32 + quad * 8];
            int kidx = (kk >> 5) + ks;
            const u16* bb = Bp + Bpbase + ((size_t)kidx * 8 * 64 + lane) * 8;
            #pragma unroll
            for (int ct = 0; ct < 8; ++ct) {
                bf16x8 b = *(const bf16x8*)(bb + (size_t)ct * 64 * 8);
                acc[0][ct] = __builtin_amdgcn_mfma_f32_16x16x32_bf16(a0, b, acc[0][ct], 0, 0, 0);
                acc[1][ct] = __builtin_amdgcn_mfma_f32_16x16x32_bf16(a1, b, acc[1][ct], 0, 0, 0);
            }
        }
        __syncthreads();
    }

    // ---- epilogue: bias (+residual) -> fp32 Out (+bf16 OutBF) ----
    #pragma unroll
    for (int rt = 0; rt < 2; ++rt) {
        int rbase = m0 + w * 32 + rt * 16 + quad * 4;
        #pragma unroll
        for (int reg = 0; reg < 4; ++reg) {
            int grow = rbase + reg;
            if (grow >= M) continue;
            size_t rrow = 0;
            if (RES) rrow = (size_t)(res_map ? res_map[grow] : grow) * HDIM;
            #pragma unroll
            for (int ct = 0; ct < 8; ++ct) {
                int col = ct * 16 + cl;
                float v = acc[rt][ct][reg] + loadF(bias, biasoff + col, f32);
                if (RES) v += Resid[rrow + col];
                Out[(size_t)grow * HDIM + col] = v;
                if (WRITE_BF) OutBF[(size_t)grow * HDIM + col] = f2bf(v);
            }
        }
    }
}

// ---------------- Final: gather -> LN -> ReLU -> pred -> log_softmax ---
__global__ __launch_bounds__(64) void final_head_kernel(
    const float* __restrict__ Hsrc, const int* __restrict__ map1,
    const int* __restrict__ fmap,
    const void* __restrict__ g, const void* __restrict__ b, int goff,
    const void* __restrict__ pw, const void* __restrict__ pb,
    const int* __restrict__ dt, void* __restrict__ out)
{
    const bool f32 = (*dt != 0);
    __shared__ float sh[HDIM];
    int i = blockIdx.x;
    int lane = threadIdx.x;
    int jj = map1[fmap[i]];
    const float2* p = (const float2*)(Hsrc + (size_t)jj * HDIM);
    float2 v = p[lane];
    float mu = wave_sum(v.x + v.y) * (1.0f / 128.0f);
    float d0 = v.x - mu, d1 = v.y - mu;
    float var = wave_sum(d0 * d0 + d1 * d1) * (1.0f / 128.0f);
    float rs = rsqrtf(var + 1e-5f);
    int f0 = lane * 2;
    sh[f0]     = fmaxf(d0 * rs * loadF(g, goff + f0, f32)     + loadF(b, goff + f0, f32),     0.0f);
    sh[f0 + 1] = fmaxf(d1 * rs * loadF(g, goff + f0 + 1, f32) + loadF(b, goff + f0 + 1, f32), 0.0f);
    __syncthreads();
    float acc = -1e30f;
    if (lane < NCLS) {
        acc = loadF(pb, lane, f32);
        #pragma unroll 4
        for (int k = 0; k < HDIM; ++k)
            acc = fmaf(sh[k], loadF(pw, k * NCLS + lane, f32), acc);
    }
    float mx = wave_max(acc);
    float ex = (lane < NCLS) ? __expf(acc - mx) : 0.0f;
    float sum = wave_sum(ex);
    if (lane < NCLS) {
        float r = acc - mx - logf(sum);
        if (f32) ((float*)out)[(size_t)i * NCLS + lane] = r;
        else     ((u16*)out)[(size_t)i * NCLS + lane] = f2bf(r);
    }
}

extern "C" void kernel_launch(void* const* d_in, const int* in_sizes, int n_in,
                              void* d_out, int out_size, void* d_ws, size_t ws_size,
                              hipStream_t stream) {
    const void* x       = d_in[0];
    const int* src      = (const int*)d_in[1];
    const int* dst      = (const int*)d_in[2];
    const int* node_map = (const int*)d_in[3];
    const int* fmap     = (const int*)d_in[4];
    const void* enc_w   = d_in[5];
    const void* enc_b   = d_in[6];
    const void* gcn_w   = d_in[7];
    const void* gcn_b   = d_in[8];
    const void* ln_g    = d_in[9];
    const void* ln_b    = d_in[10];
    const void* pred_w  = d_in[11];
    const void* pred_b  = d_in[12];

    char* ws = (char*)d_ws;
    const size_t szP = (size_t)N_NODES * HDIM * sizeof(float);   // 51.2 MB
    float* P0  = (float*)ws;  ws += szP;
    float* P1  = (float*)ws;  ws += szP;
    float* AGG = (float*)ws;  ws += szP;
    u16*   HB  = (u16*)ws;    ws += (size_t)N_NODES * HDIM * 2;  // 25.6 MB
    int*   FLAG = (int*)ws;   ws += 1024;
    u16*   Bp  = (u16*)ws;    ws += (size_t)(32768 + 3 * 16384) * 2 + 1024;
    const size_t szI = ((size_t)(N_NODES + 2) * 4 + 1023) & ~1023ull;
    int* deg0  = (int*)ws;  ws += szI;
    int* rp0   = (int*)ws;  ws += szI;
    int* cur0  = (int*)ws;  ws += szI;
    int* ei0   = (int*)ws;  ws += (size_t)N_EDGES * 4;
    int* deg1  = (int*)ws;  ws += szI;
    int* rp1   = (int*)ws;  ws += szI;
    int* cur1  = (int*)ws;  ws += szI;
    int* ei1   = (int*)ws;  ws += (size_t)N_EDGES * 4;
    int* csum  = (int*)ws;  ws += 1024;
    int* coff  = (int*)ws;  ws += 1024;

    dim3 blk(256);
    const int ggrid = (N_NODES + 127) / 128;
    const int egrid = (N_EDGES + 255) / 256;
    const int lgrid = (N_NODES + 3) / 4;
    const int pgrid = (32768 + 3 * 16384 + 255) / 256;

    dtype_detect_kernel<<<1, blk, 0, stream>>>((const u16*)x, FLAG);
    pack_b_kernel<<<pgrid, blk, 0, stream>>>(enc_w, gcn_w, FLAG, Bp);

    // ---- CSR for edge list 0 (layers 0 and 1) ----
    hipMemsetAsync(deg0, 0, szI, stream);
    hist_kernel<<<egrid, blk, 0, stream>>>(dst, deg0);
    chunk_sum_kernel<<<NCHUNK, blk, 0, stream>>>(deg0, csum);
    chunk_off_kernel<<<1, blk, 0, stream>>>(csum, coff);
    scan_write_kernel<<<NCHUNK, blk, 0, stream>>>(deg0, coff, rp0, cur0);
    scatter_kernel<<<egrid, blk, 0, stream>>>(src, dst, cur0, ei0);
    // ---- CSR for edge list 1 (layer 2) ----
    hipMemsetAsync(deg1, 0, szI, stream);
    hist_kernel<<<egrid, blk, 0, stream>>>(dst + N_EDGES, deg1);
    chunk_sum_kernel<<<NCHUNK, blk, 0, stream>>>(deg1, csum);
    chunk_off_kernel<<<1, blk, 0, stream>>>(csum, coff);
    scan_write_kernel<<<NCHUNK, blk, 0, stream>>>(deg1, coff, rp1, cur1);
    scatter_kernel<<<egrid, blk, 0, stream>>>(src + N_EDGES, dst + N_EDGES, cur1, ei1);

    // encoder: P0 = x @ enc_w + enc_b ; HB = bf16(P0)
    gemm_kernel<0, false, true><<<ggrid, blk, 0, stream>>>(
        x, nullptr, nullptr, nullptr, Bp, 0, enc_b, 0, nullptr, nullptr, FLAG,
        P0, HB, N_NODES, FIN_D);

    // conv0: AGG from CSR0 over HB; P1 = (AGG + P0) @ w0 + b0
    agg_kernel<<<lgrid, blk, 0, stream>>>(rp0, ei0, HB, AGG);
    gemm_kernel<1, false, false><<<ggrid, blk, 0, stream>>>(
        nullptr, AGG, P0, nullptr, Bp, 32768, gcn_b, 0, nullptr, nullptr, FLAG,
        P1, nullptr, N_NODES, HDIM);

    // layer 1: HB = relu(LN(P1, ln0)); AGG from CSR0; P0 = (AGG+HB)@w1+b1 + P1
    ln_relu_kernel<<<lgrid, blk, 0, stream>>>(P1, nullptr, ln_g, ln_b, 0, FLAG, HB);
    agg_kernel<<<lgrid, blk, 0, stream>>>(rp0, ei0, HB, AGG);
    gemm_kernel<2, true, false><<<ggrid, blk, 0, stream>>>(
        nullptr, AGG, nullptr, HB, Bp, 32768 + 16384, gcn_b, 128, P1, nullptr, FLAG,
        P0, nullptr, N_NODES, HDIM);

    // layer 2: rows via node_map[0]; CSR1; P1 = (AGG+HB)@w2+b2 + P0[map]
    ln_relu_kernel<<<lgrid, blk, 0, stream>>>(P0, node_map, ln_g, ln_b, 128, FLAG, HB);
    agg_kernel<<<lgrid, blk, 0, stream>>>(rp1, ei1, HB, AGG);
    gemm_kernel<2, true, false><<<ggrid, blk, 0, stream>>>(
        nullptr, AGG, nullptr, HB, Bp, 32768 + 2 * 16384, gcn_b, 256, P0, node_map, FLAG,
        P1, nullptr, N_NODES, HDIM);

    // final head
    final_head_kernel<<<NOUT_D, dim3(64), 0, stream>>>(
        P1, node_map + N_NODES, fmap, ln_g, ln_b, 256, pred_w, pred_b, FLAG,
        (void*)d_out);
}